// Round 1
// baseline (213.174 us; speedup 1.0000x reference)
//
#include <hip/hip_runtime.h>
#include <hip/hip_bf16.h>

// CrossModalContrastiveLoss: B=8, C=256, H=W=32 -> N=8192 vectors of dim 256.
// loss = -( P - 1024 * sum_i log(sum_j exp(S_ij)) ) / 8388608,
// S = normalize(rgb) @ normalize(x)^T / 0.1, P = sum of S over positive mask
// (positive: col%8 == row/1024). Fused: never materialize S.

#define HWsz 1024
#define Cdim 256
#define Nvec 8192
#define CHW  (Cdim * HWsz)

typedef __attribute__((ext_vector_type(8))) short bf16x8;
typedef __attribute__((ext_vector_type(4))) float f32x4;

__device__ inline unsigned short f2bf(float f) {
  unsigned int u = __float_as_uint(f);
  u += 0x7FFFu + ((u >> 16) & 1u);   // round-to-nearest-even
  return (unsigned short)(u >> 16);
}

// One thread per output vector n = b*1024 + hw. Reads are coalesced across
// lanes (consecutive lanes -> consecutive hw -> consecutive addresses).
__global__ __launch_bounds__(256) void norm_kernel(
    const float* __restrict__ rgb, const float* __restrict__ x,
    unsigned short* __restrict__ rgbn, unsigned short* __restrict__ xn) {
  const int n = blockIdx.x * 256 + threadIdx.x;
  const float* src = (blockIdx.y == 0) ? rgb : x;
  unsigned short* dst = (blockIdx.y == 0) ? rgbn : xn;
  const int b = n >> 10;
  const int hw = n & 1023;
  const float* p = src + (size_t)b * CHW + hw;

  float ss = 0.f;
#pragma unroll 8
  for (int c = 0; c < Cdim; ++c) {
    float v = p[(size_t)c * HWsz];
    ss += v * v;
  }
  const float inv = 1.0f / fmaxf(sqrtf(ss), 1e-12f);

  unsigned short* drow = dst + (size_t)n * Cdim;
  for (int c0 = 0; c0 < Cdim; c0 += 8) {
    unsigned short tmp[8];
#pragma unroll
    for (int j = 0; j < 8; ++j)
      tmp[j] = f2bf(p[(size_t)(c0 + j) * HWsz] * inv);
    *reinterpret_cast<uint4*>(&drow[c0]) = *reinterpret_cast<const uint4*>(tmp);
  }
}

// 128x128 tile NT GEMM (A=(N,C) rgb_n, B=(N,C) x_n, both row-major, K=256),
// fused exp-rowsum + positive-sum epilogue. 256 threads = 4 waves in 2x2.
__global__ __launch_bounds__(256) void gemm_loss_kernel(
    const unsigned short* __restrict__ A, const unsigned short* __restrict__ Bm,
    float* __restrict__ sumexp, float* __restrict__ Pacc) {
  __shared__ unsigned short sA[128 * 64];
  __shared__ unsigned short sB[128 * 64];
  __shared__ float rows_exp[128];
  __shared__ float pos_s;

  const int tid  = threadIdx.x;
  const int lane = tid & 63;
  const int w    = tid >> 6;   // wave id 0..3
  const int wm   = w & 1;      // row half
  const int wn   = w >> 1;     // col half
  const int brow = blockIdx.x;
  const int bcol = blockIdx.y;

  f32x4 acc[4][4];
#pragma unroll
  for (int i = 0; i < 4; ++i)
#pragma unroll
    for (int j = 0; j < 4; ++j) acc[i][j] = (f32x4){0.f, 0.f, 0.f, 0.f};

  const int srow = tid >> 3;        // 0..31 (wave w covers w*8 .. w*8+7)
  const int scol = (tid & 7) * 8;   // element offset in K

  for (int kc = 0; kc < 4; ++kc) {
    const int k0 = kc * 64;
#pragma unroll
    for (int s = 0; s < 4; ++s) {
      const unsigned short* gp =
          A + (size_t)(brow * 128 + s * 32 + srow) * Cdim + k0 + scol;
      unsigned short* lp = &sA[(s * 32 + w * 8) * 64];  // wave-uniform base
      __builtin_amdgcn_global_load_lds(
          (const __attribute__((address_space(1))) void*)gp,
          (__attribute__((address_space(3))) void*)lp, 16, 0, 0);
    }
#pragma unroll
    for (int s = 0; s < 4; ++s) {
      const unsigned short* gp =
          Bm + (size_t)(bcol * 128 + s * 32 + srow) * Cdim + k0 + scol;
      unsigned short* lp = &sB[(s * 32 + w * 8) * 64];
      __builtin_amdgcn_global_load_lds(
          (const __attribute__((address_space(1))) void*)gp,
          (__attribute__((address_space(3))) void*)lp, 16, 0, 0);
    }
    __syncthreads();

#pragma unroll
    for (int ks = 0; ks < 2; ++ks) {
      bf16x8 af[4], bfr[4];
#pragma unroll
      for (int mi = 0; mi < 4; ++mi) {
        const int row = wm * 64 + mi * 16 + (lane & 15);
        af[mi] = *reinterpret_cast<const bf16x8*>(
            &sA[row * 64 + ks * 32 + (lane >> 4) * 8]);
      }
#pragma unroll
      for (int ni = 0; ni < 4; ++ni) {
        const int col = wn * 64 + ni * 16 + (lane & 15);
        bfr[ni] = *reinterpret_cast<const bf16x8*>(
            &sB[col * 64 + ks * 32 + (lane >> 4) * 8]);
      }
#pragma unroll
      for (int mi = 0; mi < 4; ++mi)
#pragma unroll
        for (int ni = 0; ni < 4; ++ni)
          acc[mi][ni] = __builtin_amdgcn_mfma_f32_16x16x32_bf16(
              af[mi], bfr[ni], acc[mi][ni], 0, 0, 0);
    }
    __syncthreads();
  }

  // ---- fused epilogue ----
  if (tid < 128) rows_exp[tid] = 0.f;
  if (tid == 0) pos_s = 0.f;
  __syncthreads();

  const float scale = 10.0f;                 // 1 / TEMPERATURE
  const int bsel = brow >> 3;                // i/1024, constant per block
  const bool ispos = ((lane & 7) == bsel);   // col%8 == lane&7
  const int q = lane >> 4;
  float posloc = 0.f;

#pragma unroll
  for (int mi = 0; mi < 4; ++mi) {
#pragma unroll
    for (int r = 0; r < 4; ++r) {
      float se = 0.f;
#pragma unroll
      for (int ni = 0; ni < 4; ++ni) {
        const float v = scale * acc[mi][ni][r];
        se += __expf(v);
        if (ispos) posloc += v;
      }
      // reduce across the 16 lanes holding this row (same q group)
      se += __shfl_xor(se, 1);
      se += __shfl_xor(se, 2);
      se += __shfl_xor(se, 4);
      se += __shfl_xor(se, 8);
      if ((lane & 15) == 0) {
        const int row = wm * 64 + mi * 16 + q * 4 + r;
        atomicAdd(&rows_exp[row], se);
      }
    }
  }
  posloc += __shfl_xor(posloc, 1);
  posloc += __shfl_xor(posloc, 2);
  posloc += __shfl_xor(posloc, 4);
  posloc += __shfl_xor(posloc, 8);
  posloc += __shfl_xor(posloc, 16);
  posloc += __shfl_xor(posloc, 32);
  if (lane == 0) atomicAdd(&pos_s, posloc);
  __syncthreads();

  if (tid < 128) atomicAdd(&sumexp[brow * 128 + tid], rows_exp[tid]);
  if (tid == 0) atomicAdd(Pacc, pos_s);
}

__global__ __launch_bounds__(256) void finalize_kernel(
    const float* __restrict__ sumexp, const float* __restrict__ Pacc,
    float* __restrict__ out) {
  __shared__ float part[4];
  float lsum = 0.f;
  for (int i = threadIdx.x; i < Nvec; i += 256) lsum += logf(sumexp[i]);
  lsum += __shfl_xor(lsum, 1);
  lsum += __shfl_xor(lsum, 2);
  lsum += __shfl_xor(lsum, 4);
  lsum += __shfl_xor(lsum, 8);
  lsum += __shfl_xor(lsum, 16);
  lsum += __shfl_xor(lsum, 32);
  const int wv = threadIdx.x >> 6;
  if ((threadIdx.x & 63) == 0) part[wv] = lsum;
  __syncthreads();
  if (threadIdx.x == 0) {
    const float total_lse = part[0] + part[1] + part[2] + part[3];
    const float P = Pacc[0];
    const float loss = -(P - 1024.0f * total_lse) / (8388608.0f + 1e-8f);
    out[0] = loss;  // WEIGHT = 1.0
  }
}

extern "C" void kernel_launch(void* const* d_in, const int* in_sizes, int n_in,
                              void* d_out, int out_size, void* d_ws,
                              size_t ws_size, hipStream_t stream) {
  const float* rgb = (const float*)d_in[0];
  const float* x   = (const float*)d_in[1];
  char* ws = (char*)d_ws;
  unsigned short* rgbn = (unsigned short*)ws;                            // 4 MiB
  unsigned short* xn   = (unsigned short*)(ws + (size_t)4 * 1024 * 1024);// 4 MiB
  float* sumexp = (float*)(ws + (size_t)8 * 1024 * 1024);                // 32 KiB
  float* Pacc   = sumexp + Nvec;

  hipMemsetAsync(sumexp, 0, Nvec * sizeof(float) + 16, stream);
  norm_kernel<<<dim3(32, 2), 256, 0, stream>>>(rgb, x, rgbn, xn);
  gemm_loss_kernel<<<dim3(64, 64), 256, 0, stream>>>(rgbn, xn, sumexp, Pacc);
  finalize_kernel<<<1, 256, 0, stream>>>(sumexp, Pacc, (float*)d_out);
}

// Round 2
// 151.746 us; speedup vs baseline: 1.4048x; 1.4048x over previous
//
#include <hip/hip_runtime.h>
#include <hip/hip_bf16.h>

// CrossModalContrastiveLoss: B=8, C=256, H=W=32 -> N=8192 vectors of dim 256.
// loss = -( P - 1024 * sum_i log(sum_j exp(S_ij)) ) / 8388608,
// S = normalize(rgb) @ normalize(x)^T / 0.1, P = sum of S over positive mask
// (positive: col%8 == row/1024). Fused: never materialize S.

#define HWsz 1024
#define Cdim 256
#define Nvec 8192
#define CHW  (Cdim * HWsz)

typedef __attribute__((ext_vector_type(8))) short bf16x8;
typedef __attribute__((ext_vector_type(4))) float f32x4;

__device__ inline unsigned short f2bf(float f) {
  unsigned int u = __float_as_uint(f);
  u += 0x7FFFu + ((u >> 16) & 1u);   // round-to-nearest-even
  return (unsigned short)(u >> 16);
}

// 32 vectors per block, C split 8 ways (32 channels/thread, cached in regs).
// grid (256, 2): 512 blocks = 2048 waves -> latency hidden, ~1 global pass.
__global__ __launch_bounds__(256) void norm_kernel(
    const float* __restrict__ rgb, const float* __restrict__ x,
    unsigned short* __restrict__ rgbn, unsigned short* __restrict__ xn) {
  __shared__ float ssp[8][32];
  const int t = threadIdx.x;
  const int nl = t & 31;        // vector within block
  const int part = t >> 5;      // 0..7: channel chunk
  const float* src = (blockIdx.y == 0) ? rgb : x;
  unsigned short* dst = (blockIdx.y == 0) ? rgbn : xn;
  const int n = blockIdx.x * 32 + nl;
  const int b = n >> 10;
  const int hw = n & 1023;
  const float* p = src + (size_t)b * CHW + (size_t)(part * 32) * HWsz + hw;

  float v[32];
  float ss = 0.f;
#pragma unroll
  for (int j = 0; j < 32; ++j) {
    v[j] = p[(size_t)j * HWsz];
    ss += v[j] * v[j];
  }
  ssp[part][nl] = ss;
  __syncthreads();
  float tot = 0.f;
#pragma unroll
  for (int q = 0; q < 8; ++q) tot += ssp[q][nl];
  const float inv = 1.0f / fmaxf(sqrtf(tot), 1e-12f);

  unsigned short* drow = dst + (size_t)n * Cdim + part * 32;
#pragma unroll
  for (int c0 = 0; c0 < 32; c0 += 8) {
    unsigned short tmp[8];
#pragma unroll
    for (int j = 0; j < 8; ++j) tmp[j] = f2bf(v[c0 + j] * inv);
    *reinterpret_cast<uint4*>(&drow[c0]) = *reinterpret_cast<const uint4*>(tmp);
  }
}

// 128x128 tile NT GEMM (A=(N,C) rgb_n, B=(N,C) x_n, both row-major, K=256),
// fused exp-rowsum + positive-sum epilogue. 256 threads = 4 waves in 2x2.
// LDS layout XOR-swizzled: tile (row, colgroup cg) holds global k-group
// cg ^ (row & 7)  (cg = 8-short / 16-byte unit). This keeps global_load_lds's
// lane-contiguous constraint while making quad fragment reads conflict-free.
__global__ __launch_bounds__(256) void gemm_loss_kernel(
    const unsigned short* __restrict__ A, const unsigned short* __restrict__ Bm,
    float* __restrict__ sumexp, float* __restrict__ Pacc) {
  __shared__ unsigned short sA[128 * 64];
  __shared__ unsigned short sB[128 * 64];
  __shared__ float rows_exp[128];
  __shared__ float pos_s;

  const int tid  = threadIdx.x;
  const int lane = tid & 63;
  const int w    = tid >> 6;   // wave id 0..3
  const int wm   = w & 1;      // row half
  const int wn   = w >> 1;     // col half
  const int brow = blockIdx.x;
  const int bcol = blockIdx.y;

  f32x4 acc[4][4];
#pragma unroll
  for (int i = 0; i < 4; ++i)
#pragma unroll
    for (int j = 0; j < 4; ++j) acc[i][j] = (f32x4){0.f, 0.f, 0.f, 0.f};

  const int srow = tid >> 3;                              // 0..31 within grp
  const int scol = (((tid & 7) ^ (srow & 7)) * 8);        // swizzled k-offset

  for (int kc = 0; kc < 4; ++kc) {
    const int k0 = kc * 64;
#pragma unroll
    for (int s = 0; s < 4; ++s) {
      const unsigned short* gp =
          A + (size_t)(brow * 128 + s * 32 + srow) * Cdim + k0 + scol;
      unsigned short* lp = &sA[(s * 32 + w * 8) * 64];  // wave-uniform base
      __builtin_amdgcn_global_load_lds(
          (const __attribute__((address_space(1))) void*)gp,
          (__attribute__((address_space(3))) void*)lp, 16, 0, 0);
    }
#pragma unroll
    for (int s = 0; s < 4; ++s) {
      const unsigned short* gp =
          Bm + (size_t)(bcol * 128 + s * 32 + srow) * Cdim + k0 + scol;
      unsigned short* lp = &sB[(s * 32 + w * 8) * 64];
      __builtin_amdgcn_global_load_lds(
          (const __attribute__((address_space(1))) void*)gp,
          (__attribute__((address_space(3))) void*)lp, 16, 0, 0);
    }
    __syncthreads();

#pragma unroll
    for (int ks = 0; ks < 2; ++ks) {
      // swizzled column group: row&7 == lane&7 for both A and B fragments
      const int cg = ((ks * 4 + (lane >> 4)) ^ (lane & 7)) * 8;
      bf16x8 af[4], bfr[4];
#pragma unroll
      for (int mi = 0; mi < 4; ++mi) {
        const int row = wm * 64 + mi * 16 + (lane & 15);
        af[mi] = *reinterpret_cast<const bf16x8*>(&sA[row * 64 + cg]);
      }
#pragma unroll
      for (int ni = 0; ni < 4; ++ni) {
        const int col = wn * 64 + ni * 16 + (lane & 15);
        bfr[ni] = *reinterpret_cast<const bf16x8*>(&sB[col * 64 + cg]);
      }
#pragma unroll
      for (int mi = 0; mi < 4; ++mi)
#pragma unroll
        for (int ni = 0; ni < 4; ++ni)
          acc[mi][ni] = __builtin_amdgcn_mfma_f32_16x16x32_bf16(
              af[mi], bfr[ni], acc[mi][ni], 0, 0, 0);
    }
    __syncthreads();
  }

  // ---- fused epilogue ----
  if (tid < 128) rows_exp[tid] = 0.f;
  if (tid == 0) pos_s = 0.f;
  __syncthreads();

  const float scale = 10.0f;                 // 1 / TEMPERATURE
  const int bsel = brow >> 3;                // i/1024, constant per block
  const bool ispos = ((lane & 7) == bsel);   // col%8 == lane&7
  const int q = lane >> 4;
  float posloc = 0.f;

#pragma unroll
  for (int mi = 0; mi < 4; ++mi) {
#pragma unroll
    for (int r = 0; r < 4; ++r) {
      float se = 0.f;
#pragma unroll
      for (int ni = 0; ni < 4; ++ni) {
        const float v = scale * acc[mi][ni][r];
        se += __expf(v);
        if (ispos) posloc += v;
      }
      // reduce across the 16 lanes holding this row (same q group)
      se += __shfl_xor(se, 1);
      se += __shfl_xor(se, 2);
      se += __shfl_xor(se, 4);
      se += __shfl_xor(se, 8);
      if ((lane & 15) == 0) {
        const int row = wm * 64 + mi * 16 + q * 4 + r;
        atomicAdd(&rows_exp[row], se);
      }
    }
  }
  posloc += __shfl_xor(posloc, 1);
  posloc += __shfl_xor(posloc, 2);
  posloc += __shfl_xor(posloc, 4);
  posloc += __shfl_xor(posloc, 8);
  posloc += __shfl_xor(posloc, 16);
  posloc += __shfl_xor(posloc, 32);
  if (lane == 0) atomicAdd(&pos_s, posloc);
  __syncthreads();

  if (tid < 128) atomicAdd(&sumexp[brow * 128 + tid], rows_exp[tid]);
  if (tid == 0) atomicAdd(Pacc, pos_s);
}

__global__ __launch_bounds__(256) void finalize_kernel(
    const float* __restrict__ sumexp, const float* __restrict__ Pacc,
    float* __restrict__ out) {
  __shared__ float part[4];
  float lsum = 0.f;
  for (int i = threadIdx.x; i < Nvec; i += 256) lsum += logf(sumexp[i]);
  lsum += __shfl_xor(lsum, 1);
  lsum += __shfl_xor(lsum, 2);
  lsum += __shfl_xor(lsum, 4);
  lsum += __shfl_xor(lsum, 8);
  lsum += __shfl_xor(lsum, 16);
  lsum += __shfl_xor(lsum, 32);
  const int wv = threadIdx.x >> 6;
  if ((threadIdx.x & 63) == 0) part[wv] = lsum;
  __syncthreads();
  if (threadIdx.x == 0) {
    const float total_lse = part[0] + part[1] + part[2] + part[3];
    const float P = Pacc[0];
    const float loss = -(P - 1024.0f * total_lse) / (8388608.0f + 1e-8f);
    out[0] = loss;  // WEIGHT = 1.0
  }
}

extern "C" void kernel_launch(void* const* d_in, const int* in_sizes, int n_in,
                              void* d_out, int out_size, void* d_ws,
                              size_t ws_size, hipStream_t stream) {
  const float* rgb = (const float*)d_in[0];
  const float* x   = (const float*)d_in[1];
  char* ws = (char*)d_ws;
  unsigned short* rgbn = (unsigned short*)ws;                            // 4 MiB
  unsigned short* xn   = (unsigned short*)(ws + (size_t)4 * 1024 * 1024);// 4 MiB
  float* sumexp = (float*)(ws + (size_t)8 * 1024 * 1024);                // 32 KiB
  float* Pacc   = sumexp + Nvec;

  hipMemsetAsync(sumexp, 0, Nvec * sizeof(float) + 16, stream);
  norm_kernel<<<dim3(256, 2), 256, 0, stream>>>(rgb, x, rgbn, xn);
  gemm_loss_kernel<<<dim3(64, 64), 256, 0, stream>>>(rgbn, xn, sumexp, Pacc);
  finalize_kernel<<<1, 256, 0, stream>>>(sumexp, Pacc, (float*)d_out);
}